// Round 1
// baseline (117.379 us; speedup 1.0000x reference)
//
#include <hip/hip_runtime.h>

// Haar IDWT, fully collapsed:
//   out[b, oi, oj] = 0.5 * ( (ll+lh) + sgn_j*hl + sgn_i*sgn_j*hh )
//   coeffs at (b, oi>>1, oj>>1, 0..3); sgn_i=+1 iff oi odd; sgn_j=+1 iff oj odd.
// Symmetric padding in the reference is never sampled after the crop -> no
// boundary handling. Input NHWC C=4 -> one float4 per coeff site.
//
// v2: grid capped at 2048 blocks (256 CU x 8), hardcoded 4-iter unrolled
// grid-stride loop (2^21 items / 2^19 threads exactly), nontemporal loads
// and stores (zero reuse; poison fill flushes L3 between iterations anyway).
// Each iteration: 2 contiguous float4 loads (32 B/lane), 2 contiguous
// float4 stores (row pair). Every memory instruction is fully coalesced
// across the wave (1-2 KiB per instruction).

typedef float f4 __attribute__((ext_vector_type(4)));

__global__ __launch_bounds__(256) void idwt_haar_kernel(
        const float* __restrict__ in, float* __restrict__ out) {
    constexpr int STRIDE = 2048 * 256;   // threads in grid = 2^19
    int tid0 = blockIdx.x * 256 + threadIdx.x;

#pragma unroll
    for (int it = 0; it < 4; ++it) {
        int tid = tid0 + it * STRIDE;
        int xq = tid & 255;          // coefficient column-pair index: x = 2*xq, 2*xq+1
        int y  = (tid >> 8) & 511;   // coefficient row
        int b  = tid >> 17;          // batch

        const f4* in4 = reinterpret_cast<const f4*>(in)
                      + ((size_t)(b * 512 + y) * 512 + xq * 2);
        f4 c0 = __builtin_nontemporal_load(in4);
        f4 c1 = __builtin_nontemporal_load(in4 + 1);

        // c.x=ll, c.y=lh, c.z=hl, c.w=hh  (reference fuses ll+lh by linearity)
        float a0 = c0.x + c0.y, h0 = c0.z, d0 = c0.w;
        float a1 = c1.x + c1.y, h1 = c1.z, d1 = c1.w;

        f4 top, bot;
        // even output row (oi=2y): sgn_i=-1 ; cols: even->sgn_j=-1, odd->sgn_j=+1
        top.x = 0.5f * (a0 - h0 + d0);
        top.y = 0.5f * (a0 + h0 - d0);
        top.z = 0.5f * (a1 - h1 + d1);
        top.w = 0.5f * (a1 + h1 - d1);
        // odd output row (oi=2y+1): sgn_i=+1
        bot.x = 0.5f * (a0 - h0 - d0);
        bot.y = 0.5f * (a0 + h0 + d0);
        bot.z = 0.5f * (a1 - h1 - d1);
        bot.w = 0.5f * (a1 + h1 + d1);

        size_t obase = ((size_t)b * 1024 + 2 * y) * 1024 + 4 * xq;
        __builtin_nontemporal_store(top, reinterpret_cast<f4*>(out + obase));
        __builtin_nontemporal_store(bot, reinterpret_cast<f4*>(out + obase + 1024));
    }
}

extern "C" void kernel_launch(void* const* d_in, const int* in_sizes, int n_in,
                              void* d_out, int out_size, void* d_ws, size_t ws_size,
                              hipStream_t stream) {
    const float* in = (const float*)d_in[0];
    float* out = (float*)d_out;
    idwt_haar_kernel<<<2048, 256, 0, stream>>>(in, out);
}

// Round 2
// 107.649 us; speedup vs baseline: 1.0904x; 1.0904x over previous
//
#include <hip/hip_runtime.h>

// Haar IDWT, fully collapsed:
//   out[b, oi, oj] = 0.5 * ( (ll+lh) + sgn_j*hl + sgn_i*sgn_j*hh )
//   coeffs at (b, oi>>1, oj>>1, 0..3); sgn_i=+1 iff oi odd; sgn_j=+1 iff oj odd.
// Symmetric padding in the reference is never sampled after the crop -> no
// boundary handling. Input NHWC C=4 -> one float4 per coeff site.
//
// v3: ONE site per thread, one-shot grid (v1 launch structure).
//   - load: single float4, 16 B/lane unit-stride -> every wave-load is a
//     dense 1 KiB segment (v1's 2x32B pattern touched each 128B line from
//     TWO instructions; this halves load-path transactions).
//   - store: 2x float2 (rows 2y, 2y+1), 8 B/lane unit-stride dense
//     (512 B/instruction; same total store-path line count as v1).
// No nontemporal, no grid-stride (the v2 bundle regressed ~6.5 us).

typedef float f2 __attribute__((ext_vector_type(2)));

__global__ __launch_bounds__(256) void idwt_haar_kernel(
        const float* __restrict__ in, float* __restrict__ out) {
    int tid = blockIdx.x * 256 + threadIdx.x;
    int x = tid & 511;           // coefficient column
    int y = (tid >> 9) & 511;    // coefficient row
    int b = tid >> 18;           // batch

    const float4* in4 = reinterpret_cast<const float4*>(in)
                      + ((size_t)(b * 512 + y) * 512 + x);
    float4 c = *in4;

    // c.x=ll, c.y=lh, c.z=hl, c.w=hh  (reference fuses ll+lh by linearity)
    float a = c.x + c.y, h = c.z, d = c.w;

    f2 top, bot;
    // even output row (oi=2y): sgn_i=-1 ; cols: even->sgn_j=-1, odd->sgn_j=+1
    top.x = 0.5f * (a - h + d);
    top.y = 0.5f * (a + h - d);
    // odd output row (oi=2y+1): sgn_i=+1
    bot.x = 0.5f * (a - h - d);
    bot.y = 0.5f * (a + h + d);

    size_t obase = ((size_t)b * 1024 + 2 * y) * 1024 + 2 * x;
    *reinterpret_cast<f2*>(out + obase)        = top;
    *reinterpret_cast<f2*>(out + obase + 1024) = bot;
}

extern "C" void kernel_launch(void* const* d_in, const int* in_sizes, int n_in,
                              void* d_out, int out_size, void* d_ws, size_t ws_size,
                              hipStream_t stream) {
    const float* in = (const float*)d_in[0];
    float* out = (float*)d_out;
    // total threads: 16 batches * 512 rows * 512 cols = 4,194,304
    int total = 16 * 512 * 512;
    idwt_haar_kernel<<<total / 256, 256, 0, stream>>>(in, out);
}